// Round 4
// baseline (340.693 us; speedup 1.0000x reference)
//
#include <hip/hip_runtime.h>
#include <hip/hip_bf16.h>
#include <math.h>

typedef unsigned short u16;
typedef __bf16 bf16_t;
typedef bf16_t bf16x8 __attribute__((ext_vector_type(8)));
typedef float f32x4 __attribute__((ext_vector_type(4)));

#define N_HEADC 16
#define C_EMBD  1024
#define B_SZ    4
#define T_SEQ   2048
#define HD      64
#define M_TOT   (B_SZ * T_SEQ)   // 8192

__device__ __forceinline__ u16 f2b(float f) {
    unsigned u = __float_as_uint(f);
    u = u + 0x7fffu + ((u >> 16) & 1u);   // round-to-nearest-even
    return (u16)(u >> 16);
}
// HW packed f32x2 -> bf16x2 (RNE), single VALU op (gfx940+)
__device__ __forceinline__ unsigned pkbf16(float a, float b) {
    unsigned d;
    asm("v_cvt_pk_bf16_f32 %0, %1, %2" : "=v"(d) : "v"(a), "v"(b));
    return d;
}
__device__ __forceinline__ float fexp2(float x) {
#if __has_builtin(__builtin_amdgcn_exp2f)
    return __builtin_amdgcn_exp2f(x);
#else
    return exp2f(x);
#endif
}
// async global->LDS, 16B per lane; LDS dest = wave-uniform base + lane*16
__device__ __forceinline__ void gl_lds16(const u16* g, u16* l) {
    __builtin_amdgcn_global_load_lds(
        (const __attribute__((address_space(1))) unsigned int*)g,
        (__attribute__((address_space(3))) unsigned int*)l,
        16, 0, 0);
}

// ---------------- prep kernels ----------------

__global__ __launch_bounds__(256) void cast_f32_to_bf16(const float* __restrict__ in,
                                                        u16* __restrict__ out) {
    int i = (blockIdx.x * 256 + threadIdx.x) * 4;
    float4 v = *(const float4*)(in + i);
    ushort4 o;
    o.x = f2b(v.x); o.y = f2b(v.y); o.z = f2b(v.z); o.w = f2b(v.w);
    *(ushort4*)(out + i) = o;
}

// in: [K][N] fp32 row-major -> out: [N][K] bf16 row-major
__global__ __launch_bounds__(256) void transpose_cast(const float* __restrict__ in,
                                                      u16* __restrict__ out,
                                                      int K, int N) {
    __shared__ float tile[32][33];
    int n0 = blockIdx.x * 32, k0 = blockIdx.y * 32;
    for (int i = threadIdx.y; i < 32; i += 8)
        tile[i][threadIdx.x] = in[(size_t)(k0 + i) * N + n0 + threadIdx.x];
    __syncthreads();
    for (int i = threadIdx.y; i < 32; i += 8)
        out[(size_t)(n0 + i) * K + k0 + threadIdx.x] = f2b(tile[threadIdx.x][i]);
}

// bf16 transpose per head: qV [BH][T][64] -> qVt [BH][64][T]
// grid (T/64, B*H), block 256. LDS tile [64][66] (even stride, odd dword
// stride 33 -> conflict-free-ish; same-word u16 pairs broadcast).
__global__ __launch_bounds__(256) void transpose_v(const u16* __restrict__ qV,
                                                   u16* __restrict__ qVt) {
    __shared__ u16 tile[64][66];
    int t0 = blockIdx.x * 64;
    size_t base = (size_t)blockIdx.y * T_SEQ * HD;
    int tid = threadIdx.x;
    #pragma unroll
    for (int c = 0; c < 2; ++c) {
        int ch = tid * 2 + c;
        int row = ch >> 3, off = (ch & 7) * 8;
        uint4 v = *(const uint4*)&qV[base + (size_t)(t0 + row) * HD + off];
        const unsigned* pv = (const unsigned*)&v;
        #pragma unroll
        for (int e = 0; e < 4; ++e)
            *(unsigned*)&tile[row][off + e * 2] = pv[e];
    }
    __syncthreads();
    int d = tid >> 2, tq = tid & 3;
    u16 vals[16];
    #pragma unroll
    for (int k = 0; k < 16; ++k) vals[k] = tile[tq * 16 + k][d];
    *(uint4*)&qVt[base + (size_t)d * T_SEQ + t0 + tq * 16] = *(uint4*)&vals[0];
    *(uint4*)&qVt[base + (size_t)d * T_SEQ + t0 + tq * 16 + 8] = *(uint4*)&vals[8];
}

// ---------------- MFMA GEMM: qkv ----------------
// 128x128 tile, BK=32, 4 waves, global_load_lds(16B) staging.
// A-frag: m=lane&15, k=quad*8+j ; C/D: row=quad*4+reg, col=lane&15.
// Epilogue: Q scaled by 0.125*log2(e); Q,K,V all written [B][H][T][hd]
// (coalesced 2B stores); V transposed to [hd][T] by transpose_v afterwards.
__global__ __launch_bounds__(256) void gemm_qkv(const u16* __restrict__ A,   // [8192][1024]
                                                const u16* __restrict__ BT,  // [3072][1024]
                                                const float* __restrict__ bias, // [3072]
                                                u16* __restrict__ qQ,
                                                u16* __restrict__ qK,
                                                u16* __restrict__ qV) {
    const int K = C_EMBD;
    __shared__ __align__(16) u16 sA[128 * 32];
    __shared__ __align__(16) u16 sB[128 * 32];
    int m0 = blockIdx.y * 128;
    int n0 = blockIdx.x * 128;
    int tid = threadIdx.x;
    int w = tid >> 6, lane = tid & 63;
    int m_off = (w & 1) * 64, n_off = (w >> 1) * 64;
    int quad = lane >> 4, rl = lane & 15;

    f32x4 acc[4][4];
    #pragma unroll
    for (int i = 0; i < 4; ++i)
        #pragma unroll
        for (int j = 0; j < 4; ++j)
            acc[i][j] = f32x4{0.f, 0.f, 0.f, 0.f};

    int srow = lane >> 2, sko = (lane & 3) * 8;

    for (int k0 = 0; k0 < K; k0 += 32) {
        #pragma unroll
        for (int c = 0; c < 4; ++c) {
            int rb = ((w & 1) * 4 + c) * 16;
            if (w < 2)
                gl_lds16(&A[(size_t)(m0 + rb + srow) * K + k0 + sko], &sA[rb * 32]);
            else
                gl_lds16(&BT[(size_t)(n0 + rb + srow) * K + k0 + sko], &sB[rb * 32]);
        }
        __syncthreads();
        bf16x8 af[4], bfr[4];
        #pragma unroll
        for (int i = 0; i < 4; ++i)
            af[i] = *(const bf16x8*)&sA[(m_off + i * 16 + rl) * 32 + quad * 8];
        #pragma unroll
        for (int j = 0; j < 4; ++j)
            bfr[j] = *(const bf16x8*)&sB[(n_off + j * 16 + rl) * 32 + quad * 8];
        #pragma unroll
        for (int i = 0; i < 4; ++i)
            #pragma unroll
            for (int j = 0; j < 4; ++j)
                acc[i][j] = __builtin_amdgcn_mfma_f32_16x16x32_bf16(af[i], bfr[j], acc[i][j], 0, 0, 0);
        __syncthreads();
    }

    const float QSC = 0.18033688011112042f;   // 0.125 * log2(e)
    #pragma unroll
    for (int j = 0; j < 4; ++j) {
        int n = n0 + n_off + j * 16 + rl;
        float bv = bias[n];
        int p = n >> 10, cch = n & 1023;
        int h = cch >> 6, d = cch & 63;
        u16* dst = p == 0 ? qQ : (p == 1 ? qK : qV);
        float sc = p == 0 ? QSC : 1.0f;
        #pragma unroll
        for (int i = 0; i < 4; ++i) {
            int mbase = m0 + m_off + i * 16 + quad * 4;
            int bb = mbase >> 11, t0 = mbase & 2047;
            size_t thbase = ((size_t)bb * N_HEADC + h) * T_SEQ;
            #pragma unroll
            for (int r = 0; r < 4; ++r)
                dst[(thbase + t0 + r) * HD + d] = f2b((acc[i][j][r] + bv) * sc);
        }
    }
}

// proj: A = y_attn bf16 [8192][1024], BT = WprojT, out fp32 + bias
__global__ __launch_bounds__(256) void gemm_proj(const u16* __restrict__ A,
                                                 const u16* __restrict__ BT,
                                                 const float* __restrict__ bias,
                                                 float* __restrict__ out) {
    const int K = C_EMBD;
    __shared__ __align__(16) u16 sA[128 * 32];
    __shared__ __align__(16) u16 sB[128 * 32];
    int m0 = blockIdx.y * 128;
    int n0 = blockIdx.x * 128;
    int tid = threadIdx.x;
    int w = tid >> 6, lane = tid & 63;
    int m_off = (w & 1) * 64, n_off = (w >> 1) * 64;
    int quad = lane >> 4, rl = lane & 15;

    f32x4 acc[4][4];
    #pragma unroll
    for (int i = 0; i < 4; ++i)
        #pragma unroll
        for (int j = 0; j < 4; ++j)
            acc[i][j] = f32x4{0.f, 0.f, 0.f, 0.f};

    int srow = lane >> 2, sko = (lane & 3) * 8;

    for (int k0 = 0; k0 < K; k0 += 32) {
        #pragma unroll
        for (int c = 0; c < 4; ++c) {
            int rb = ((w & 1) * 4 + c) * 16;
            if (w < 2)
                gl_lds16(&A[(size_t)(m0 + rb + srow) * K + k0 + sko], &sA[rb * 32]);
            else
                gl_lds16(&BT[(size_t)(n0 + rb + srow) * K + k0 + sko], &sB[rb * 32]);
        }
        __syncthreads();
        bf16x8 af[4], bfr[4];
        #pragma unroll
        for (int i = 0; i < 4; ++i)
            af[i] = *(const bf16x8*)&sA[(m_off + i * 16 + rl) * 32 + quad * 8];
        #pragma unroll
        for (int j = 0; j < 4; ++j)
            bfr[j] = *(const bf16x8*)&sB[(n_off + j * 16 + rl) * 32 + quad * 8];
        #pragma unroll
        for (int i = 0; i < 4; ++i)
            #pragma unroll
            for (int j = 0; j < 4; ++j)
                acc[i][j] = __builtin_amdgcn_mfma_f32_16x16x32_bf16(af[i], bfr[j], acc[i][j], 0, 0, 0);
        __syncthreads();
    }

    #pragma unroll
    for (int i = 0; i < 4; ++i) {
        int mbase = m0 + m_off + i * 16 + quad * 4;
        #pragma unroll
        for (int j = 0; j < 4; ++j) {
            int n = n0 + n_off + j * 16 + rl;
            float bv = bias[n];
            #pragma unroll
            for (int r = 0; r < 4; ++r)
                out[(size_t)(mbase + r) * C_EMBD + n] = acc[i][j][r] + bv;
        }
    }
}

// ---------------- MFMA flash attention (causal, static-M softmax) ----------------
// grid (16, H, B) LPT order: block bx handles qt = 15-bx (longest first);
// 1024 blocks, 52.2 KB LDS -> 3 blocks/CU resident.
// S^T = K.Q^T with C = -M folded into the accumulator -> p = exp2(s) direct.
// P packed via v_cvt_pk_bf16_f32; sP stride 76 u16 (2-way banks = free).
// K/Vt double-buffered via global_load_lds (prefetch kt+1 overlaps compute).
__global__ __launch_bounds__(256) void attn_mfma(const u16* __restrict__ Qg,
                                                 const u16* __restrict__ Kg,
                                                 const u16* __restrict__ Vtg,
                                                 u16* __restrict__ yb) {
    int qt = 15 - blockIdx.x, h = blockIdx.y, b = blockIdx.z;
    const size_t hs = (size_t)T_SEQ * HD;
    const u16* Qp  = Qg  + ((size_t)b * N_HEADC + h) * hs;  // [T][64] (pre-scaled)
    const u16* Kp  = Kg  + ((size_t)b * N_HEADC + h) * hs;  // [T][64]
    const u16* Vtp = Vtg + ((size_t)b * N_HEADC + h) * hs;  // [64][T]

    __shared__ __align__(16) u16 sK[2][2][64][32];   // [buf][d-half][kpos][d32]
    __shared__ __align__(16) u16 sVt[2][2][64][32];  // [buf][k-half][d][k32]
    __shared__ __align__(16) u16 sP[4][32][76];      // per-wave [q32][kpos64+pad12]

    int tid = threadIdx.x;
    int lane = tid & 63, w = tid >> 6;
    int quad = lane >> 4, rl = lane & 15;
    u16* sPw = &sP[w][0][0];
    int srow = lane >> 2;            // staging: row within 16-row chunk
    int sch = (lane & 3) * 8;        // staging: 8-elem piece
    const f32x4 mneg = {-16.f, -16.f, -16.f, -16.f};   // -SOFT_M folded into C
    int q0w = qt * 128 + w * 32;
    int nkt = 2 * qt + 2;

    // Q fragments (B-operand of S^T)
    bf16x8 qf[2][2];
    #pragma unroll
    for (int nt = 0; nt < 2; ++nt)
        #pragma unroll
        for (int ks = 0; ks < 2; ++ks)
            qf[nt][ks] = *(const bf16x8*)&Qp[(size_t)(q0w + nt * 16 + rl) * HD + ks * 32 + quad * 8];

    f32x4 O[2][4];
    #pragma unroll
    for (int mi = 0; mi < 2; ++mi)
        #pragma unroll
        for (int nd = 0; nd < 4; ++nd)
            O[mi][nd] = f32x4{0.f, 0.f, 0.f, 0.f};
    float l_[2] = {0.f, 0.f};

    // stage kt=0 into buf 0  (4 x 1KB chunks per wave: K 8KB + Vt 8KB)
    #pragma unroll
    for (int c = 0; c < 4; ++c) {
        int lc = w * 4 + c;
        int ks = (lc >> 2) & 1;
        int rb = (lc & 3) * 16;
        if (lc < 8)
            gl_lds16(Kp + (size_t)(rb + srow) * HD + ks * 32 + sch, &sK[0][ks][rb][0]);
        else
            gl_lds16(Vtp + (size_t)(rb + srow) * T_SEQ + ks * 32 + sch, &sVt[0][ks][rb][0]);
    }

    for (int kt = 0; kt < nkt; ++kt) {
        __syncthreads();          // drains stage(kt); syncs buffers
        int buf = kt & 1;
        int k0 = kt * 64;
        if (kt + 1 < nkt) {       // prefetch kt+1 into other buffer (overlaps compute)
            int k1 = k0 + 64;
            #pragma unroll
            for (int c = 0; c < 4; ++c) {
                int lc = w * 4 + c;
                int ks = (lc >> 2) & 1;
                int rb = (lc & 3) * 16;
                if (lc < 8)
                    gl_lds16(Kp + (size_t)(k1 + rb + srow) * HD + ks * 32 + sch,
                             &sK[buf ^ 1][ks][rb][0]);
                else
                    gl_lds16(Vtp + (size_t)(rb + srow) * T_SEQ + k1 + ks * 32 + sch,
                             &sVt[buf ^ 1][ks][rb][0]);
            }
        }
        if (k0 > q0w + 31) continue;   // this wave's rows fully masked

        // S^T = K . Q^T - M : rows kpos=k0+mt*16+quad*4+r, col q=q0w+nt*16+rl
        f32x4 st[4][2];
        #pragma unroll
        for (int mt = 0; mt < 4; ++mt) {
            bf16x8 ak0 = *(const bf16x8*)&sK[buf][0][mt * 16 + rl][quad * 8];
            bf16x8 ak1 = *(const bf16x8*)&sK[buf][1][mt * 16 + rl][quad * 8];
            #pragma unroll
            for (int nt = 0; nt < 2; ++nt) {
                f32x4 t = __builtin_amdgcn_mfma_f32_16x16x32_bf16(ak0, qf[nt][0], mneg, 0, 0, 0);
                st[mt][nt] = __builtin_amdgcn_mfma_f32_16x16x32_bf16(ak1, qf[nt][1], t, 0, 0, 0);
            }
        }

        if (k0 + 63 > q0w) {   // diagonal tile: causal mask
            #pragma unroll
            for (int mt = 0; mt < 4; ++mt)
                #pragma unroll
                for (int nt = 0; nt < 2; ++nt)
                    #pragma unroll
                    for (int r = 0; r < 4; ++r) {
                        int kpos = k0 + mt * 16 + quad * 4 + r;
                        int q = q0w + nt * 16 + rl;
                        if (kpos > q) st[mt][nt][r] = -INFINITY;
                    }
        }

        // static-M softmax: p = exp2(s); lane-local l accumulation
        #pragma unroll
        for (int nt = 0; nt < 2; ++nt) {
            float lsum = 0.f;
            #pragma unroll
            for (int mt = 0; mt < 4; ++mt) {
                float p0 = fexp2(st[mt][nt][0]);
                float p1 = fexp2(st[mt][nt][1]);
                float p2 = fexp2(st[mt][nt][2]);
                float p3 = fexp2(st[mt][nt][3]);
                lsum += (p0 + p1) + (p2 + p3);
                *(uint2*)&sPw[(nt * 16 + rl) * 76 + mt * 16 + quad * 4] =
                    make_uint2(pkbf16(p0, p1), pkbf16(p2, p3));
            }
            l_[nt] += lsum;
        }

        // O += P . V  (A=P from own LDS region, B=V^T)
        #pragma unroll
        for (int ks = 0; ks < 2; ++ks) {
            bf16x8 ap0 = *(const bf16x8*)&sPw[(0 * 16 + rl) * 76 + ks * 32 + quad * 8];
            bf16x8 ap1 = *(const bf16x8*)&sPw[(1 * 16 + rl) * 76 + ks * 32 + quad * 8];
            #pragma unroll
            for (int nd = 0; nd < 4; ++nd) {
                bf16x8 bv = *(const bf16x8*)&sVt[buf][ks][nd * 16 + rl][quad * 8];
                O[0][nd] = __builtin_amdgcn_mfma_f32_16x16x32_bf16(ap0, bv, O[0][nd], 0, 0, 0);
                O[1][nd] = __builtin_amdgcn_mfma_f32_16x16x32_bf16(ap1, bv, O[1][nd], 0, 0, 0);
            }
        }
    }

    // epilogue: reduce l across quads, write y[b*T+q][h*64+d] = O/l
    #pragma unroll
    for (int nt = 0; nt < 2; ++nt) {
        l_[nt] += __shfl_xor(l_[nt], 16);
        l_[nt] += __shfl_xor(l_[nt], 32);
    }
    float linv[2] = {1.f / l_[0], 1.f / l_[1]};
    int idxq = quad * 4;
    #pragma unroll
    for (int mi = 0; mi < 2; ++mi)
        #pragma unroll
        for (int r = 0; r < 4; ++r) {
            float li = __shfl(linv[mi], idxq + r);
            int qg = q0w + mi * 16 + quad * 4 + r;
            size_t base = ((size_t)b * T_SEQ + qg) * C_EMBD + h * HD;
            #pragma unroll
            for (int nd = 0; nd < 4; ++nd)
                yb[base + nd * 16 + rl] = f2b(O[mi][nd][r] * li);
        }
}

// ---------------- launch ----------------
// workspace layout (bytes):
//   xb     @ 0      : 16 MB  bf16 [8192][1024]
//   WqkvT  @ 16 MB  :  6 MB  bf16 [3072][1024]
//   WprojT @ 22 MB  :  2 MB  bf16 [1024][1024]
//   qQ     @ 24 MB  : 16 MB  bf16 [B][H][T][64] (pre-scaled by 0.125*log2e)
//   qK     @ 40 MB  : 16 MB  bf16 [B][H][T][64]
//   qVt    @ 56 MB  : 16 MB  bf16 [B][H][64][T]
//   yb     @ 72 MB  : 16 MB  bf16 [8192][1024]  (doubles as qV staging:
//                     gemm_qkv writes V here, transpose_v copies to qVt,
//                     then attn overwrites it with y — in-stream ordered)
extern "C" void kernel_launch(void* const* d_in, const int* in_sizes, int n_in,
                              void* d_out, int out_size, void* d_ws, size_t ws_size,
                              hipStream_t stream) {
    const float* x     = (const float*)d_in[0];
    const float* Wqkv  = (const float*)d_in[1];
    const float* bqkv  = (const float*)d_in[2];
    const float* Wproj = (const float*)d_in[3];
    const float* bproj = (const float*)d_in[4];
    float* out = (float*)d_out;

    char* ws = (char*)d_ws;
    u16* xb     = (u16*)(ws);
    u16* WqkvT  = (u16*)(ws + (size_t)16 * 1024 * 1024);
    u16* WprojT = (u16*)(ws + (size_t)22 * 1024 * 1024);
    u16* qQ     = (u16*)(ws + (size_t)24 * 1024 * 1024);
    u16* qK     = (u16*)(ws + (size_t)40 * 1024 * 1024);
    u16* qVt    = (u16*)(ws + (size_t)56 * 1024 * 1024);
    u16* yb     = (u16*)(ws + (size_t)72 * 1024 * 1024);
    u16* qV     = yb;   // reuse: dead once transpose_v completes

    cast_f32_to_bf16<<<dim3(M_TOT * C_EMBD / (256 * 4)), dim3(256), 0, stream>>>(x, xb);
    transpose_cast<<<dim3(3 * C_EMBD / 32, C_EMBD / 32), dim3(32, 8), 0, stream>>>(
        Wqkv, WqkvT, C_EMBD, 3 * C_EMBD);
    transpose_cast<<<dim3(C_EMBD / 32, C_EMBD / 32), dim3(32, 8), 0, stream>>>(
        Wproj, WprojT, C_EMBD, C_EMBD);
    gemm_qkv<<<dim3(3 * C_EMBD / 128, M_TOT / 128), dim3(256), 0, stream>>>(
        xb, WqkvT, bqkv, qQ, qK, qV);
    transpose_v<<<dim3(T_SEQ / 64, B_SZ * N_HEADC), dim3(256), 0, stream>>>(qV, qVt);
    attn_mfma<<<dim3(16, N_HEADC, B_SZ), dim3(256), 0, stream>>>(
        qQ, qK, qVt, yb);
    gemm_proj<<<dim3(C_EMBD / 128, M_TOT / 128), dim3(256), 0, stream>>>(
        yb, WprojT, bproj, out);
}

// Round 5
// 293.668 us; speedup vs baseline: 1.1601x; 1.1601x over previous
//
#include <hip/hip_runtime.h>
#include <hip/hip_bf16.h>
#include <math.h>

typedef unsigned short u16;
typedef __bf16 bf16_t;
typedef bf16_t bf16x8 __attribute__((ext_vector_type(8)));
typedef float f32x4 __attribute__((ext_vector_type(4)));

#define N_HEADC 16
#define C_EMBD  1024
#define B_SZ    4
#define T_SEQ   2048
#define HD      64
#define M_TOT   (B_SZ * T_SEQ)   // 8192

__device__ __forceinline__ u16 f2b(float f) {
    unsigned u = __float_as_uint(f);
    u = u + 0x7fffu + ((u >> 16) & 1u);   // round-to-nearest-even
    return (u16)(u >> 16);
}
// HW packed f32x2 -> bf16x2 (RNE), single VALU op (gfx940+)
__device__ __forceinline__ unsigned pkbf16(float a, float b) {
    unsigned d;
    asm("v_cvt_pk_bf16_f32 %0, %1, %2" : "=v"(d) : "v"(a), "v"(b));
    return d;
}
__device__ __forceinline__ float fexp2(float x) {
#if __has_builtin(__builtin_amdgcn_exp2f)
    return __builtin_amdgcn_exp2f(x);
#else
    return exp2f(x);
#endif
}
// async global->LDS, 16B per lane; LDS dest = wave-uniform base + lane*16
__device__ __forceinline__ void gl_lds16(const u16* g, u16* l) {
    __builtin_amdgcn_global_load_lds(
        (const __attribute__((address_space(1))) unsigned int*)g,
        (__attribute__((address_space(3))) unsigned int*)l,
        16, 0, 0);
}

// ---------------- prep kernels ----------------

__global__ __launch_bounds__(256) void cast_f32_to_bf16(const float* __restrict__ in,
                                                        u16* __restrict__ out) {
    int i = (blockIdx.x * 256 + threadIdx.x) * 4;
    float4 v = *(const float4*)(in + i);
    ushort4 o;
    o.x = f2b(v.x); o.y = f2b(v.y); o.z = f2b(v.z); o.w = f2b(v.w);
    *(ushort4*)(out + i) = o;
}

// in: [K][N] fp32 row-major -> out: [N][K] bf16 row-major
__global__ __launch_bounds__(256) void transpose_cast(const float* __restrict__ in,
                                                      u16* __restrict__ out,
                                                      int K, int N) {
    __shared__ float tile[32][33];
    int n0 = blockIdx.x * 32, k0 = blockIdx.y * 32;
    for (int i = threadIdx.y; i < 32; i += 8)
        tile[i][threadIdx.x] = in[(size_t)(k0 + i) * N + n0 + threadIdx.x];
    __syncthreads();
    for (int i = threadIdx.y; i < 32; i += 8)
        out[(size_t)(n0 + i) * K + k0 + threadIdx.x] = f2b(tile[threadIdx.x][i]);
}

// bf16 transpose per head: qV [BH][T][64] -> qVt [BH][64][T]
__global__ __launch_bounds__(256) void transpose_v(const u16* __restrict__ qV,
                                                   u16* __restrict__ qVt) {
    __shared__ u16 tile[64][66];
    int t0 = blockIdx.x * 64;
    size_t base = (size_t)blockIdx.y * T_SEQ * HD;
    int tid = threadIdx.x;
    #pragma unroll
    for (int c = 0; c < 2; ++c) {
        int ch = tid * 2 + c;
        int row = ch >> 3, off = (ch & 7) * 8;
        uint4 v = *(const uint4*)&qV[base + (size_t)(t0 + row) * HD + off];
        const unsigned* pv = (const unsigned*)&v;
        #pragma unroll
        for (int e = 0; e < 4; ++e)
            *(unsigned*)&tile[row][off + e * 2] = pv[e];
    }
    __syncthreads();
    int d = tid >> 2, tq = tid & 3;
    u16 vals[16];
    #pragma unroll
    for (int k = 0; k < 16; ++k) vals[k] = tile[tq * 16 + k][d];
    *(uint4*)&qVt[base + (size_t)d * T_SEQ + t0 + tq * 16] = *(uint4*)&vals[0];
    *(uint4*)&qVt[base + (size_t)d * T_SEQ + t0 + tq * 16 + 8] = *(uint4*)&vals[8];
}

// ---------------- MFMA GEMM: qkv ----------------
// 128x128 tile, BK=32, 4 waves, uint4-VGPR staging (R1-proven; gl_lds variant
// regressed ~90us — see R4 post-mortem).
// A-frag: m=lane&15, k=quad*8+j ; C/D: row=quad*4+reg, col=lane&15.
// Epilogue: Q scaled by 0.125*log2(e); Q,K,V written [B][H][T][hd] coalesced;
// V transposed to [hd][T] by transpose_v afterwards.
__global__ __launch_bounds__(256) void gemm_qkv(const u16* __restrict__ A,   // [8192][1024]
                                                const u16* __restrict__ BT,  // [3072][1024]
                                                const float* __restrict__ bias, // [3072]
                                                u16* __restrict__ qQ,
                                                u16* __restrict__ qK,
                                                u16* __restrict__ qV) {
    const int K = C_EMBD;
    __shared__ __align__(16) u16 sA[128 * 32];
    __shared__ __align__(16) u16 sB[128 * 32];
    int m0 = blockIdx.y * 128;
    int n0 = blockIdx.x * 128;
    int tid = threadIdx.x;
    int w = tid >> 6, lane = tid & 63;
    int m_off = (w & 1) * 64, n_off = (w >> 1) * 64;
    int quad = lane >> 4, rl = lane & 15;

    f32x4 acc[4][4];
    #pragma unroll
    for (int i = 0; i < 4; ++i)
        #pragma unroll
        for (int j = 0; j < 4; ++j)
            acc[i][j] = f32x4{0.f, 0.f, 0.f, 0.f};

    for (int k0 = 0; k0 < K; k0 += 32) {
        #pragma unroll
        for (int c = 0; c < 2; ++c) {
            int ch = tid * 2 + c;            // 512 chunks of 8 bf16
            int row = ch >> 2, ko = (ch & 3) * 8;
            *(uint4*)&sA[row * 32 + ko] = *(const uint4*)&A[(size_t)(m0 + row) * K + k0 + ko];
            *(uint4*)&sB[row * 32 + ko] = *(const uint4*)&BT[(size_t)(n0 + row) * K + k0 + ko];
        }
        __syncthreads();
        bf16x8 af[4], bfr[4];
        #pragma unroll
        for (int i = 0; i < 4; ++i)
            af[i] = *(const bf16x8*)&sA[(m_off + i * 16 + rl) * 32 + quad * 8];
        #pragma unroll
        for (int j = 0; j < 4; ++j)
            bfr[j] = *(const bf16x8*)&sB[(n_off + j * 16 + rl) * 32 + quad * 8];
        #pragma unroll
        for (int i = 0; i < 4; ++i)
            #pragma unroll
            for (int j = 0; j < 4; ++j)
                acc[i][j] = __builtin_amdgcn_mfma_f32_16x16x32_bf16(af[i], bfr[j], acc[i][j], 0, 0, 0);
        __syncthreads();
    }

    const float QSC = 0.18033688011112042f;   // 0.125 * log2(e)
    #pragma unroll
    for (int j = 0; j < 4; ++j) {
        int n = n0 + n_off + j * 16 + rl;
        float bv = bias[n];
        int p = n >> 10, cch = n & 1023;
        int h = cch >> 6, d = cch & 63;
        u16* dst = p == 0 ? qQ : (p == 1 ? qK : qV);
        float sc = p == 0 ? QSC : 1.0f;
        #pragma unroll
        for (int i = 0; i < 4; ++i) {
            int mbase = m0 + m_off + i * 16 + quad * 4;
            int bb = mbase >> 11, t0 = mbase & 2047;
            size_t thbase = ((size_t)bb * N_HEADC + h) * T_SEQ;
            #pragma unroll
            for (int r = 0; r < 4; ++r)
                dst[(thbase + t0 + r) * HD + d] = f2b((acc[i][j][r] + bv) * sc);
        }
    }
}

// proj: A = y_attn bf16 [8192][1024], BT = WprojT, out fp32 + bias
__global__ __launch_bounds__(256) void gemm_proj(const u16* __restrict__ A,
                                                 const u16* __restrict__ BT,
                                                 const float* __restrict__ bias,
                                                 float* __restrict__ out) {
    const int K = C_EMBD;
    __shared__ __align__(16) u16 sA[128 * 32];
    __shared__ __align__(16) u16 sB[128 * 32];
    int m0 = blockIdx.y * 128;
    int n0 = blockIdx.x * 128;
    int tid = threadIdx.x;
    int w = tid >> 6, lane = tid & 63;
    int m_off = (w & 1) * 64, n_off = (w >> 1) * 64;
    int quad = lane >> 4, rl = lane & 15;

    f32x4 acc[4][4];
    #pragma unroll
    for (int i = 0; i < 4; ++i)
        #pragma unroll
        for (int j = 0; j < 4; ++j)
            acc[i][j] = f32x4{0.f, 0.f, 0.f, 0.f};

    for (int k0 = 0; k0 < K; k0 += 32) {
        #pragma unroll
        for (int c = 0; c < 2; ++c) {
            int ch = tid * 2 + c;
            int row = ch >> 2, ko = (ch & 3) * 8;
            *(uint4*)&sA[row * 32 + ko] = *(const uint4*)&A[(size_t)(m0 + row) * K + k0 + ko];
            *(uint4*)&sB[row * 32 + ko] = *(const uint4*)&BT[(size_t)(n0 + row) * K + k0 + ko];
        }
        __syncthreads();
        bf16x8 af[4], bfr[4];
        #pragma unroll
        for (int i = 0; i < 4; ++i)
            af[i] = *(const bf16x8*)&sA[(m_off + i * 16 + rl) * 32 + quad * 8];
        #pragma unroll
        for (int j = 0; j < 4; ++j)
            bfr[j] = *(const bf16x8*)&sB[(n_off + j * 16 + rl) * 32 + quad * 8];
        #pragma unroll
        for (int i = 0; i < 4; ++i)
            #pragma unroll
            for (int j = 0; j < 4; ++j)
                acc[i][j] = __builtin_amdgcn_mfma_f32_16x16x32_bf16(af[i], bfr[j], acc[i][j], 0, 0, 0);
        __syncthreads();
    }

    #pragma unroll
    for (int i = 0; i < 4; ++i) {
        int mbase = m0 + m_off + i * 16 + quad * 4;
        #pragma unroll
        for (int j = 0; j < 4; ++j) {
            int n = n0 + n_off + j * 16 + rl;
            float bv = bias[n];
            #pragma unroll
            for (int r = 0; r < 4; ++r)
                out[(size_t)(mbase + r) * C_EMBD + n] = acc[i][j][r] + bv;
        }
    }
}

// ---------------- MFMA flash attention (causal, static-M softmax) ----------------
// grid (8, H, B), block 256 = 4 waves. Block bx does q-tiles (15-bx) then bx
// -> every block runs exactly 34 k-iterations (uniform length beats LPT:
// R4's 1024-singles grid drained into a low-occupancy tail, 147us vs 80us).
// S^T = K.Q^T with C = -M folded into the accumulator -> p = exp2(s) direct.
// P packed via v_cvt_pk_bf16_f32; sP stride 72 u16 (16B-aligned b128 reads).
// K/Vt double-buffered via global_load_lds (prefetch kt+1 overlaps compute).
__global__ __launch_bounds__(256) void attn_mfma(const u16* __restrict__ Qg,
                                                 const u16* __restrict__ Kg,
                                                 const u16* __restrict__ Vtg,
                                                 u16* __restrict__ yb) {
    int bx = blockIdx.x, h = blockIdx.y, b = blockIdx.z;
    const size_t hs = (size_t)T_SEQ * HD;
    const u16* Qp  = Qg  + ((size_t)b * N_HEADC + h) * hs;  // [T][64] (pre-scaled)
    const u16* Kp  = Kg  + ((size_t)b * N_HEADC + h) * hs;  // [T][64]
    const u16* Vtp = Vtg + ((size_t)b * N_HEADC + h) * hs;  // [64][T]

    __shared__ __align__(16) u16 sK[2][2][64][32];   // [buf][d-half][kpos][d32]
    __shared__ __align__(16) u16 sVt[2][2][64][32];  // [buf][k-half][d][k32]
    __shared__ __align__(16) u16 sP[4][32][72];      // per-wave [q32][kpos64+pad8]

    int tid = threadIdx.x;
    int lane = tid & 63, w = tid >> 6;
    int quad = lane >> 4, rl = lane & 15;
    u16* sPw = &sP[w][0][0];
    int srow = lane >> 2;            // staging: row within 16-row chunk
    int sch = (lane & 3) * 8;        // staging: 8-elem piece
    const f32x4 mneg = {-16.f, -16.f, -16.f, -16.f};   // -SOFT_M folded into C

    #pragma unroll
    for (int phase = 0; phase < 2; ++phase) {
        int qt = phase == 0 ? (15 - bx) : bx;
        int q0w = qt * 128 + w * 32;
        int nkt = 2 * qt + 2;

        // Q fragments (B-operand of S^T)
        bf16x8 qf[2][2];
        #pragma unroll
        for (int nt = 0; nt < 2; ++nt)
            #pragma unroll
            for (int ks = 0; ks < 2; ++ks)
                qf[nt][ks] = *(const bf16x8*)&Qp[(size_t)(q0w + nt * 16 + rl) * HD + ks * 32 + quad * 8];

        f32x4 O[2][4];
        #pragma unroll
        for (int mi = 0; mi < 2; ++mi)
            #pragma unroll
            for (int nd = 0; nd < 4; ++nd)
                O[mi][nd] = f32x4{0.f, 0.f, 0.f, 0.f};
        float l_[2] = {0.f, 0.f};

        __syncthreads();   // prev phase's readers done before restaging buf0
        // stage kt=0 into buf 0  (4 x 1KB chunks per wave: K 8KB + Vt 8KB)
        #pragma unroll
        for (int c = 0; c < 4; ++c) {
            int lc = w * 4 + c;
            int ks = (lc >> 2) & 1;
            int rb = (lc & 3) * 16;
            if (lc < 8)
                gl_lds16(Kp + (size_t)(rb + srow) * HD + ks * 32 + sch, &sK[0][ks][rb][0]);
            else
                gl_lds16(Vtp + (size_t)(rb + srow) * T_SEQ + ks * 32 + sch, &sVt[0][ks][rb][0]);
        }

        for (int kt = 0; kt < nkt; ++kt) {
            __syncthreads();          // drains stage(kt); syncs buffers
            int buf = kt & 1;
            int k0 = kt * 64;
            if (kt + 1 < nkt) {       // prefetch kt+1 into other buffer (overlaps compute)
                int k1 = k0 + 64;
                #pragma unroll
                for (int c = 0; c < 4; ++c) {
                    int lc = w * 4 + c;
                    int ks = (lc >> 2) & 1;
                    int rb = (lc & 3) * 16;
                    if (lc < 8)
                        gl_lds16(Kp + (size_t)(k1 + rb + srow) * HD + ks * 32 + sch,
                                 &sK[buf ^ 1][ks][rb][0]);
                    else
                        gl_lds16(Vtp + (size_t)(rb + srow) * T_SEQ + k1 + ks * 32 + sch,
                                 &sVt[buf ^ 1][ks][rb][0]);
                }
            }
            if (k0 > q0w + 31) continue;   // this wave's rows fully masked

            // S^T = K . Q^T - M : rows kpos=k0+mt*16+quad*4+r, col q=q0w+nt*16+rl
            f32x4 st[4][2];
            #pragma unroll
            for (int mt = 0; mt < 4; ++mt) {
                bf16x8 ak0 = *(const bf16x8*)&sK[buf][0][mt * 16 + rl][quad * 8];
                bf16x8 ak1 = *(const bf16x8*)&sK[buf][1][mt * 16 + rl][quad * 8];
                #pragma unroll
                for (int nt = 0; nt < 2; ++nt) {
                    f32x4 t = __builtin_amdgcn_mfma_f32_16x16x32_bf16(ak0, qf[nt][0], mneg, 0, 0, 0);
                    st[mt][nt] = __builtin_amdgcn_mfma_f32_16x16x32_bf16(ak1, qf[nt][1], t, 0, 0, 0);
                }
            }

            if (k0 + 63 > q0w) {   // diagonal tile: causal mask
                #pragma unroll
                for (int mt = 0; mt < 4; ++mt)
                    #pragma unroll
                    for (int nt = 0; nt < 2; ++nt)
                        #pragma unroll
                        for (int r = 0; r < 4; ++r) {
                            int kpos = k0 + mt * 16 + quad * 4 + r;
                            int q = q0w + nt * 16 + rl;
                            if (kpos > q) st[mt][nt][r] = -INFINITY;
                        }
            }

            // static-M softmax: p = exp2(s); lane-local l accumulation
            #pragma unroll
            for (int nt = 0; nt < 2; ++nt) {
                float lsum = 0.f;
                #pragma unroll
                for (int mt = 0; mt < 4; ++mt) {
                    float p0 = fexp2(st[mt][nt][0]);
                    float p1 = fexp2(st[mt][nt][1]);
                    float p2 = fexp2(st[mt][nt][2]);
                    float p3 = fexp2(st[mt][nt][3]);
                    lsum += (p0 + p1) + (p2 + p3);
                    *(uint2*)&sPw[(nt * 16 + rl) * 72 + mt * 16 + quad * 4] =
                        make_uint2(pkbf16(p0, p1), pkbf16(p2, p3));
                }
                l_[nt] += lsum;
            }

            // O += P . V  (A=P from own LDS region, B=V^T)
            #pragma unroll
            for (int ks = 0; ks < 2; ++ks) {
                bf16x8 ap0 = *(const bf16x8*)&sPw[(0 * 16 + rl) * 72 + ks * 32 + quad * 8];
                bf16x8 ap1 = *(const bf16x8*)&sPw[(1 * 16 + rl) * 72 + ks * 32 + quad * 8];
                #pragma unroll
                for (int nd = 0; nd < 4; ++nd) {
                    bf16x8 bv = *(const bf16x8*)&sVt[buf][ks][nd * 16 + rl][quad * 8];
                    O[0][nd] = __builtin_amdgcn_mfma_f32_16x16x32_bf16(ap0, bv, O[0][nd], 0, 0, 0);
                    O[1][nd] = __builtin_amdgcn_mfma_f32_16x16x32_bf16(ap1, bv, O[1][nd], 0, 0, 0);
                }
            }
        }

        // epilogue: reduce l across quads, write y[b*T+q][h*64+d] = O/l
        #pragma unroll
        for (int nt = 0; nt < 2; ++nt) {
            l_[nt] += __shfl_xor(l_[nt], 16);
            l_[nt] += __shfl_xor(l_[nt], 32);
        }
        float linv[2] = {1.f / l_[0], 1.f / l_[1]};
        int idxq = quad * 4;
        #pragma unroll
        for (int mi = 0; mi < 2; ++mi)
            #pragma unroll
            for (int r = 0; r < 4; ++r) {
                float li = __shfl(linv[mi], idxq + r);
                int qg = q0w + mi * 16 + quad * 4 + r;
                size_t base = ((size_t)b * T_SEQ + qg) * C_EMBD + h * HD;
                #pragma unroll
                for (int nd = 0; nd < 4; ++nd)
                    yb[base + nd * 16 + rl] = f2b(O[mi][nd][r] * li);
            }
    }
}

// ---------------- launch ----------------
// workspace layout (bytes):
//   xb     @ 0      : 16 MB  bf16 [8192][1024]
//   WqkvT  @ 16 MB  :  6 MB  bf16 [3072][1024]
//   WprojT @ 22 MB  :  2 MB  bf16 [1024][1024]
//   qQ     @ 24 MB  : 16 MB  bf16 [B][H][T][64] (pre-scaled by 0.125*log2e)
//   qK     @ 40 MB  : 16 MB  bf16 [B][H][T][64]
//   qVt    @ 56 MB  : 16 MB  bf16 [B][H][64][T]
//   yb     @ 72 MB  : 16 MB  bf16 [8192][1024]  (doubles as qV staging)
extern "C" void kernel_launch(void* const* d_in, const int* in_sizes, int n_in,
                              void* d_out, int out_size, void* d_ws, size_t ws_size,
                              hipStream_t stream) {
    const float* x     = (const float*)d_in[0];
    const float* Wqkv  = (const float*)d_in[1];
    const float* bqkv  = (const float*)d_in[2];
    const float* Wproj = (const float*)d_in[3];
    const float* bproj = (const float*)d_in[4];
    float* out = (float*)d_out;

    char* ws = (char*)d_ws;
    u16* xb     = (u16*)(ws);
    u16* WqkvT  = (u16*)(ws + (size_t)16 * 1024 * 1024);
    u16* WprojT = (u16*)(ws + (size_t)22 * 1024 * 1024);
    u16* qQ     = (u16*)(ws + (size_t)24 * 1024 * 1024);
    u16* qK     = (u16*)(ws + (size_t)40 * 1024 * 1024);
    u16* qVt    = (u16*)(ws + (size_t)56 * 1024 * 1024);
    u16* yb     = (u16*)(ws + (size_t)72 * 1024 * 1024);
    u16* qV     = yb;   // reuse: dead once transpose_v completes

    cast_f32_to_bf16<<<dim3(M_TOT * C_EMBD / (256 * 4)), dim3(256), 0, stream>>>(x, xb);
    transpose_cast<<<dim3(3 * C_EMBD / 32, C_EMBD / 32), dim3(32, 8), 0, stream>>>(
        Wqkv, WqkvT, C_EMBD, 3 * C_EMBD);
    transpose_cast<<<dim3(C_EMBD / 32, C_EMBD / 32), dim3(32, 8), 0, stream>>>(
        Wproj, WprojT, C_EMBD, C_EMBD);
    gemm_qkv<<<dim3(3 * C_EMBD / 128, M_TOT / 128), dim3(256), 0, stream>>>(
        xb, WqkvT, bqkv, qQ, qK, qV);
    transpose_v<<<dim3(T_SEQ / 64, B_SZ * N_HEADC), dim3(256), 0, stream>>>(qV, qVt);
    attn_mfma<<<dim3(8, N_HEADC, B_SZ), dim3(256), 0, stream>>>(
        qQ, qK, qVt, yb);
    gemm_proj<<<dim3(C_EMBD / 128, M_TOT / 128), dim3(256), 0, stream>>>(
        yb, WprojT, bproj, out);
}

// Round 6
// 274.699 us; speedup vs baseline: 1.2402x; 1.0691x over previous
//
#include <hip/hip_runtime.h>
#include <hip/hip_bf16.h>
#include <math.h>

typedef unsigned short u16;
typedef __bf16 bf16_t;
typedef bf16_t bf16x8 __attribute__((ext_vector_type(8)));
typedef float f32x4 __attribute__((ext_vector_type(4)));

#define N_HEADC 16
#define C_EMBD  1024
#define B_SZ    4
#define T_SEQ   2048
#define HD      64
#define M_TOT   (B_SZ * T_SEQ)   // 8192

__device__ __forceinline__ u16 f2b(float f) {
    unsigned u = __float_as_uint(f);
    u = u + 0x7fffu + ((u >> 16) & 1u);   // round-to-nearest-even
    return (u16)(u >> 16);
}
// HW packed f32x2 -> bf16x2 (RNE), single VALU op (gfx940+)
__device__ __forceinline__ unsigned pkbf16(float a, float b) {
    unsigned d;
    asm("v_cvt_pk_bf16_f32 %0, %1, %2" : "=v"(d) : "v"(a), "v"(b));
    return d;
}
__device__ __forceinline__ float fexp2(float x) {
#if __has_builtin(__builtin_amdgcn_exp2f)
    return __builtin_amdgcn_exp2f(x);
#else
    return exp2f(x);
#endif
}
// async global->LDS, 16B per lane; LDS dest = wave-uniform base + lane*16
__device__ __forceinline__ void gl_lds16(const u16* g, u16* l) {
    __builtin_amdgcn_global_load_lds(
        (const __attribute__((address_space(1))) unsigned int*)g,
        (__attribute__((address_space(3))) unsigned int*)l,
        16, 0, 0);
}

// ---------------- prep kernels ----------------

__global__ __launch_bounds__(256) void cast_f32_to_bf16(const float* __restrict__ in,
                                                        u16* __restrict__ out) {
    int i = (blockIdx.x * 256 + threadIdx.x) * 4;
    float4 v = *(const float4*)(in + i);
    ushort4 o;
    o.x = f2b(v.x); o.y = f2b(v.y); o.z = f2b(v.z); o.w = f2b(v.w);
    *(ushort4*)(out + i) = o;
}

// in: [K][N] fp32 row-major -> out: [N][K] bf16 row-major
__global__ __launch_bounds__(256) void transpose_cast(const float* __restrict__ in,
                                                      u16* __restrict__ out,
                                                      int K, int N) {
    __shared__ float tile[32][33];
    int n0 = blockIdx.x * 32, k0 = blockIdx.y * 32;
    for (int i = threadIdx.y; i < 32; i += 8)
        tile[i][threadIdx.x] = in[(size_t)(k0 + i) * N + n0 + threadIdx.x];
    __syncthreads();
    for (int i = threadIdx.y; i < 32; i += 8)
        out[(size_t)(n0 + i) * K + k0 + threadIdx.x] = f2b(tile[threadIdx.x][i]);
}

// bf16 transpose per head: qV [BH][T][64] -> qVt [BH][64][T]
__global__ __launch_bounds__(256) void transpose_v(const u16* __restrict__ qV,
                                                   u16* __restrict__ qVt) {
    __shared__ u16 tile[64][66];
    int t0 = blockIdx.x * 64;
    size_t base = (size_t)blockIdx.y * T_SEQ * HD;
    int tid = threadIdx.x;
    #pragma unroll
    for (int c = 0; c < 2; ++c) {
        int ch = tid * 2 + c;
        int row = ch >> 3, off = (ch & 7) * 8;
        uint4 v = *(const uint4*)&qV[base + (size_t)(t0 + row) * HD + off];
        const unsigned* pv = (const unsigned*)&v;
        #pragma unroll
        for (int e = 0; e < 4; ++e)
            *(unsigned*)&tile[row][off + e * 2] = pv[e];
    }
    __syncthreads();
    int d = tid >> 2, tq = tid & 3;
    u16 vals[16];
    #pragma unroll
    for (int k = 0; k < 16; ++k) vals[k] = tile[tq * 16 + k][d];
    *(uint4*)&qVt[base + (size_t)d * T_SEQ + t0 + tq * 16] = *(uint4*)&vals[0];
    *(uint4*)&qVt[base + (size_t)d * T_SEQ + t0 + tq * 16 + 8] = *(uint4*)&vals[8];
}

// ---------------- GEMM staging: 16KB (sA 128x32 + sB 128x32) per k-step ----
// 16 x 1KB gl_lds calls, 4 per wave (2 A-chunks + 2 B-chunks, symmetric).
__device__ __forceinline__ void stage_tile(const u16* __restrict__ A,
                                           const u16* __restrict__ BT,
                                           int rowA0, int rowB0, int k0,
                                           u16* sA, u16* sB, int w, int lane) {
    int srow = lane >> 2, sko = (lane & 3) * 8;
    #pragma unroll
    for (int c = 0; c < 2; ++c) {
        int rb = (w * 2 + c) * 16;
        gl_lds16(&A[(size_t)(rowA0 + rb + srow) * C_EMBD + k0 + sko], &sA[rb * 32]);
    }
    #pragma unroll
    for (int c = 0; c < 2; ++c) {
        int rb = (w * 2 + c) * 16;
        gl_lds16(&BT[(size_t)(rowB0 + rb + srow) * C_EMBD + k0 + sko], &sB[rb * 32]);
    }
}

// ---------------- MFMA GEMM: qkv ----------------
// 128x128 tile, BK=32, 4 waves. Double-buffered global_load_lds staging
// (attn-proven): prefetch kt+1 issued right after the barrier, overlapping
// the MFMA section on kt; ONE barrier per iteration. Barrier's vmcnt drain
// waits on loads issued a full compute-section earlier (cheap).
// A-frag: m=lane&15, k=quad*8+j ; C/D: row=quad*4+reg, col=lane&15.
__global__ __launch_bounds__(256) void gemm_qkv(const u16* __restrict__ A,   // [8192][1024]
                                                const u16* __restrict__ BT,  // [3072][1024]
                                                const float* __restrict__ bias, // [3072]
                                                u16* __restrict__ qQ,
                                                u16* __restrict__ qK,
                                                u16* __restrict__ qV) {
    const int NK = C_EMBD / 32;
    __shared__ __align__(16) u16 sA[2][128 * 32];
    __shared__ __align__(16) u16 sB[2][128 * 32];
    int m0 = blockIdx.y * 128;
    int n0 = blockIdx.x * 128;
    int tid = threadIdx.x;
    int w = tid >> 6, lane = tid & 63;
    int m_off = (w & 1) * 64, n_off = (w >> 1) * 64;
    int quad = lane >> 4, rl = lane & 15;

    f32x4 acc[4][4];
    #pragma unroll
    for (int i = 0; i < 4; ++i)
        #pragma unroll
        for (int j = 0; j < 4; ++j)
            acc[i][j] = f32x4{0.f, 0.f, 0.f, 0.f};

    stage_tile(A, BT, m0, n0, 0, sA[0], sB[0], w, lane);

    for (int kt = 0; kt < NK; ++kt) {
        __syncthreads();                       // drains prev prefetch; syncs buffers
        if (kt + 1 < NK)
            stage_tile(A, BT, m0, n0, (kt + 1) * 32,
                       sA[(kt + 1) & 1], sB[(kt + 1) & 1], w, lane);
        const u16* pA = sA[kt & 1];
        const u16* pB = sB[kt & 1];
        bf16x8 af[4], bfr[4];
        #pragma unroll
        for (int i = 0; i < 4; ++i)
            af[i] = *(const bf16x8*)&pA[(m_off + i * 16 + rl) * 32 + quad * 8];
        #pragma unroll
        for (int j = 0; j < 4; ++j)
            bfr[j] = *(const bf16x8*)&pB[(n_off + j * 16 + rl) * 32 + quad * 8];
        #pragma unroll
        for (int i = 0; i < 4; ++i)
            #pragma unroll
            for (int j = 0; j < 4; ++j)
                acc[i][j] = __builtin_amdgcn_mfma_f32_16x16x32_bf16(af[i], bfr[j], acc[i][j], 0, 0, 0);
    }

    const float QSC = 0.18033688011112042f;   // 0.125 * log2(e)
    #pragma unroll
    for (int j = 0; j < 4; ++j) {
        int n = n0 + n_off + j * 16 + rl;
        float bv = bias[n];
        int p = n >> 10, cch = n & 1023;
        int h = cch >> 6, d = cch & 63;
        u16* dst = p == 0 ? qQ : (p == 1 ? qK : qV);
        float sc = p == 0 ? QSC : 1.0f;
        #pragma unroll
        for (int i = 0; i < 4; ++i) {
            int mbase = m0 + m_off + i * 16 + quad * 4;
            int bb = mbase >> 11, t0 = mbase & 2047;
            size_t thbase = ((size_t)bb * N_HEADC + h) * T_SEQ;
            #pragma unroll
            for (int r = 0; r < 4; ++r)
                dst[(thbase + t0 + r) * HD + d] = f2b((acc[i][j][r] + bv) * sc);
        }
    }
}

// proj: A = y_attn bf16 [8192][1024], BT = WprojT, out fp32 + bias
__global__ __launch_bounds__(256) void gemm_proj(const u16* __restrict__ A,
                                                 const u16* __restrict__ BT,
                                                 const float* __restrict__ bias,
                                                 float* __restrict__ out) {
    const int NK = C_EMBD / 32;
    __shared__ __align__(16) u16 sA[2][128 * 32];
    __shared__ __align__(16) u16 sB[2][128 * 32];
    int m0 = blockIdx.y * 128;
    int n0 = blockIdx.x * 128;
    int tid = threadIdx.x;
    int w = tid >> 6, lane = tid & 63;
    int m_off = (w & 1) * 64, n_off = (w >> 1) * 64;
    int quad = lane >> 4, rl = lane & 15;

    f32x4 acc[4][4];
    #pragma unroll
    for (int i = 0; i < 4; ++i)
        #pragma unroll
        for (int j = 0; j < 4; ++j)
            acc[i][j] = f32x4{0.f, 0.f, 0.f, 0.f};

    stage_tile(A, BT, m0, n0, 0, sA[0], sB[0], w, lane);

    for (int kt = 0; kt < NK; ++kt) {
        __syncthreads();
        if (kt + 1 < NK)
            stage_tile(A, BT, m0, n0, (kt + 1) * 32,
                       sA[(kt + 1) & 1], sB[(kt + 1) & 1], w, lane);
        const u16* pA = sA[kt & 1];
        const u16* pB = sB[kt & 1];
        bf16x8 af[4], bfr[4];
        #pragma unroll
        for (int i = 0; i < 4; ++i)
            af[i] = *(const bf16x8*)&pA[(m_off + i * 16 + rl) * 32 + quad * 8];
        #pragma unroll
        for (int j = 0; j < 4; ++j)
            bfr[j] = *(const bf16x8*)&pB[(n_off + j * 16 + rl) * 32 + quad * 8];
        #pragma unroll
        for (int i = 0; i < 4; ++i)
            #pragma unroll
            for (int j = 0; j < 4; ++j)
                acc[i][j] = __builtin_amdgcn_mfma_f32_16x16x32_bf16(af[i], bfr[j], acc[i][j], 0, 0, 0);
    }

    #pragma unroll
    for (int i = 0; i < 4; ++i) {
        int mbase = m0 + m_off + i * 16 + quad * 4;
        #pragma unroll
        for (int j = 0; j < 4; ++j) {
            int n = n0 + n_off + j * 16 + rl;
            float bv = bias[n];
            #pragma unroll
            for (int r = 0; r < 4; ++r)
                out[(size_t)(mbase + r) * C_EMBD + n] = acc[i][j][r] + bv;
        }
    }
}

// ---------------- MFMA flash attention (causal, static-M softmax) ----------------
// grid (8, H, B), block 256 = 4 waves. Block bx does q-tiles (15-bx) then bx
// -> every block runs exactly 34 k-iterations (uniform length beats LPT:
// R4's 1024-singles grid drained into a low-occupancy tail, 147us vs 80us).
// S^T = K.Q^T with C = -M folded into the accumulator -> p = exp2(s) direct.
// P packed via v_cvt_pk_bf16_f32; sP stride 72 u16 (16B-aligned b128 reads).
// K/Vt double-buffered via global_load_lds (prefetch kt+1 overlaps compute).
__global__ __launch_bounds__(256) void attn_mfma(const u16* __restrict__ Qg,
                                                 const u16* __restrict__ Kg,
                                                 const u16* __restrict__ Vtg,
                                                 u16* __restrict__ yb) {
    int bx = blockIdx.x, h = blockIdx.y, b = blockIdx.z;
    const size_t hs = (size_t)T_SEQ * HD;
    const u16* Qp  = Qg  + ((size_t)b * N_HEADC + h) * hs;  // [T][64] (pre-scaled)
    const u16* Kp  = Kg  + ((size_t)b * N_HEADC + h) * hs;  // [T][64]
    const u16* Vtp = Vtg + ((size_t)b * N_HEADC + h) * hs;  // [64][T]

    __shared__ __align__(16) u16 sK[2][2][64][32];   // [buf][d-half][kpos][d32]
    __shared__ __align__(16) u16 sVt[2][2][64][32];  // [buf][k-half][d][k32]
    __shared__ __align__(16) u16 sP[4][32][72];      // per-wave [q32][kpos64+pad8]

    int tid = threadIdx.x;
    int lane = tid & 63, w = tid >> 6;
    int quad = lane >> 4, rl = lane & 15;
    u16* sPw = &sP[w][0][0];
    int srow = lane >> 2;            // staging: row within 16-row chunk
    int sch = (lane & 3) * 8;        // staging: 8-elem piece
    const f32x4 mneg = {-16.f, -16.f, -16.f, -16.f};   // -SOFT_M folded into C

    #pragma unroll
    for (int phase = 0; phase < 2; ++phase) {
        int qt = phase == 0 ? (15 - bx) : bx;
        int q0w = qt * 128 + w * 32;
        int nkt = 2 * qt + 2;

        // Q fragments (B-operand of S^T)
        bf16x8 qf[2][2];
        #pragma unroll
        for (int nt = 0; nt < 2; ++nt)
            #pragma unroll
            for (int ks = 0; ks < 2; ++ks)
                qf[nt][ks] = *(const bf16x8*)&Qp[(size_t)(q0w + nt * 16 + rl) * HD + ks * 32 + quad * 8];

        f32x4 O[2][4];
        #pragma unroll
        for (int mi = 0; mi < 2; ++mi)
            #pragma unroll
            for (int nd = 0; nd < 4; ++nd)
                O[mi][nd] = f32x4{0.f, 0.f, 0.f, 0.f};
        float l_[2] = {0.f, 0.f};

        __syncthreads();   // prev phase's readers done before restaging buf0
        // stage kt=0 into buf 0  (4 x 1KB chunks per wave: K 8KB + Vt 8KB)
        #pragma unroll
        for (int c = 0; c < 4; ++c) {
            int lc = w * 4 + c;
            int ks = (lc >> 2) & 1;
            int rb = (lc & 3) * 16;
            if (lc < 8)
                gl_lds16(Kp + (size_t)(rb + srow) * HD + ks * 32 + sch, &sK[0][ks][rb][0]);
            else
                gl_lds16(Vtp + (size_t)(rb + srow) * T_SEQ + ks * 32 + sch, &sVt[0][ks][rb][0]);
        }

        for (int kt = 0; kt < nkt; ++kt) {
            __syncthreads();          // drains stage(kt); syncs buffers
            int buf = kt & 1;
            int k0 = kt * 64;
            if (kt + 1 < nkt) {       // prefetch kt+1 into other buffer (overlaps compute)
                int k1 = k0 + 64;
                #pragma unroll
                for (int c = 0; c < 4; ++c) {
                    int lc = w * 4 + c;
                    int ks = (lc >> 2) & 1;
                    int rb = (lc & 3) * 16;
                    if (lc < 8)
                        gl_lds16(Kp + (size_t)(k1 + rb + srow) * HD + ks * 32 + sch,
                                 &sK[buf ^ 1][ks][rb][0]);
                    else
                        gl_lds16(Vtp + (size_t)(rb + srow) * T_SEQ + k1 + ks * 32 + sch,
                                 &sVt[buf ^ 1][ks][rb][0]);
                }
            }
            if (k0 > q0w + 31) continue;   // this wave's rows fully masked

            // S^T = K . Q^T - M : rows kpos=k0+mt*16+quad*4+r, col q=q0w+nt*16+rl
            f32x4 st[4][2];
            #pragma unroll
            for (int mt = 0; mt < 4; ++mt) {
                bf16x8 ak0 = *(const bf16x8*)&sK[buf][0][mt * 16 + rl][quad * 8];
                bf16x8 ak1 = *(const bf16x8*)&sK[buf][1][mt * 16 + rl][quad * 8];
                #pragma unroll
                for (int nt = 0; nt < 2; ++nt) {
                    f32x4 t = __builtin_amdgcn_mfma_f32_16x16x32_bf16(ak0, qf[nt][0], mneg, 0, 0, 0);
                    st[mt][nt] = __builtin_amdgcn_mfma_f32_16x16x32_bf16(ak1, qf[nt][1], t, 0, 0, 0);
                }
            }

            if (k0 + 63 > q0w) {   // diagonal tile: causal mask
                #pragma unroll
                for (int mt = 0; mt < 4; ++mt)
                    #pragma unroll
                    for (int nt = 0; nt < 2; ++nt)
                        #pragma unroll
                        for (int r = 0; r < 4; ++r) {
                            int kpos = k0 + mt * 16 + quad * 4 + r;
                            int q = q0w + nt * 16 + rl;
                            if (kpos > q) st[mt][nt][r] = -INFINITY;
                        }
            }

            // static-M softmax: p = exp2(s); lane-local l accumulation
            #pragma unroll
            for (int nt = 0; nt < 2; ++nt) {
                float lsum = 0.f;
                #pragma unroll
                for (int mt = 0; mt < 4; ++mt) {
                    float p0 = fexp2(st[mt][nt][0]);
                    float p1 = fexp2(st[mt][nt][1]);
                    float p2 = fexp2(st[mt][nt][2]);
                    float p3 = fexp2(st[mt][nt][3]);
                    lsum += (p0 + p1) + (p2 + p3);
                    *(uint2*)&sPw[(nt * 16 + rl) * 72 + mt * 16 + quad * 4] =
                        make_uint2(pkbf16(p0, p1), pkbf16(p2, p3));
                }
                l_[nt] += lsum;
            }

            // O += P . V  (A=P from own LDS region, B=V^T)
            #pragma unroll
            for (int ks = 0; ks < 2; ++ks) {
                bf16x8 ap0 = *(const bf16x8*)&sPw[(0 * 16 + rl) * 72 + ks * 32 + quad * 8];
                bf16x8 ap1 = *(const bf16x8*)&sPw[(1 * 16 + rl) * 72 + ks * 32 + quad * 8];
                #pragma unroll
                for (int nd = 0; nd < 4; ++nd) {
                    bf16x8 bv = *(const bf16x8*)&sVt[buf][ks][nd * 16 + rl][quad * 8];
                    O[0][nd] = __builtin_amdgcn_mfma_f32_16x16x32_bf16(ap0, bv, O[0][nd], 0, 0, 0);
                    O[1][nd] = __builtin_amdgcn_mfma_f32_16x16x32_bf16(ap1, bv, O[1][nd], 0, 0, 0);
                }
            }
        }

        // epilogue: reduce l across quads, write y[b*T+q][h*64+d] = O/l
        #pragma unroll
        for (int nt = 0; nt < 2; ++nt) {
            l_[nt] += __shfl_xor(l_[nt], 16);
            l_[nt] += __shfl_xor(l_[nt], 32);
        }
        float linv[2] = {1.f / l_[0], 1.f / l_[1]};
        int idxq = quad * 4;
        #pragma unroll
        for (int mi = 0; mi < 2; ++mi)
            #pragma unroll
            for (int r = 0; r < 4; ++r) {
                float li = __shfl(linv[mi], idxq + r);
                int qg = q0w + mi * 16 + quad * 4 + r;
                size_t base = ((size_t)b * T_SEQ + qg) * C_EMBD + h * HD;
                #pragma unroll
                for (int nd = 0; nd < 4; ++nd)
                    yb[base + nd * 16 + rl] = f2b(O[mi][nd][r] * li);
            }
    }
}

// ---------------- launch ----------------
// workspace layout (bytes):
//   xb     @ 0      : 16 MB  bf16 [8192][1024]
//   WqkvT  @ 16 MB  :  6 MB  bf16 [3072][1024]
//   WprojT @ 22 MB  :  2 MB  bf16 [1024][1024]
//   qQ     @ 24 MB  : 16 MB  bf16 [B][H][T][64] (pre-scaled by 0.125*log2e)
//   qK     @ 40 MB  : 16 MB  bf16 [B][H][T][64]
//   qVt    @ 56 MB  : 16 MB  bf16 [B][H][64][T]
//   yb     @ 72 MB  : 16 MB  bf16 [8192][1024]  (doubles as qV staging)
extern "C" void kernel_launch(void* const* d_in, const int* in_sizes, int n_in,
                              void* d_out, int out_size, void* d_ws, size_t ws_size,
                              hipStream_t stream) {
    const float* x     = (const float*)d_in[0];
    const float* Wqkv  = (const float*)d_in[1];
    const float* bqkv  = (const float*)d_in[2];
    const float* Wproj = (const float*)d_in[3];
    const float* bproj = (const float*)d_in[4];
    float* out = (float*)d_out;

    char* ws = (char*)d_ws;
    u16* xb     = (u16*)(ws);
    u16* WqkvT  = (u16*)(ws + (size_t)16 * 1024 * 1024);
    u16* WprojT = (u16*)(ws + (size_t)22 * 1024 * 1024);
    u16* qQ     = (u16*)(ws + (size_t)24 * 1024 * 1024);
    u16* qK     = (u16*)(ws + (size_t)40 * 1024 * 1024);
    u16* qVt    = (u16*)(ws + (size_t)56 * 1024 * 1024);
    u16* yb     = (u16*)(ws + (size_t)72 * 1024 * 1024);
    u16* qV     = yb;   // reuse: dead once transpose_v completes

    cast_f32_to_bf16<<<dim3(M_TOT * C_EMBD / (256 * 4)), dim3(256), 0, stream>>>(x, xb);
    transpose_cast<<<dim3(3 * C_EMBD / 32, C_EMBD / 32), dim3(32, 8), 0, stream>>>(
        Wqkv, WqkvT, C_EMBD, 3 * C_EMBD);
    transpose_cast<<<dim3(C_EMBD / 32, C_EMBD / 32), dim3(32, 8), 0, stream>>>(
        Wproj, WprojT, C_EMBD, C_EMBD);
    gemm_qkv<<<dim3(3 * C_EMBD / 128, M_TOT / 128), dim3(256), 0, stream>>>(
        xb, WqkvT, bqkv, qQ, qK, qV);
    transpose_v<<<dim3(T_SEQ / 64, B_SZ * N_HEADC), dim3(256), 0, stream>>>(qV, qVt);
    attn_mfma<<<dim3(8, N_HEADC, B_SZ), dim3(256), 0, stream>>>(
        qQ, qK, qVt, yb);
    gemm_proj<<<dim3(C_EMBD / 128, M_TOT / 128), dim3(256), 0, stream>>>(
        yb, WprojT, bproj, out);
}

// Round 7
// 259.077 us; speedup vs baseline: 1.3150x; 1.0603x over previous
//
#include <hip/hip_runtime.h>
#include <hip/hip_bf16.h>
#include <math.h>

typedef unsigned short u16;
typedef __bf16 bf16_t;
typedef bf16_t bf16x8 __attribute__((ext_vector_type(8)));
typedef float f32x4 __attribute__((ext_vector_type(4)));

#define N_HEADC 16
#define C_EMBD  1024
#define B_SZ    4
#define T_SEQ   2048
#define HD      64
#define M_TOT   (B_SZ * T_SEQ)   // 8192

__device__ __forceinline__ u16 f2b(float f) {
    unsigned u = __float_as_uint(f);
    u = u + 0x7fffu + ((u >> 16) & 1u);   // round-to-nearest-even
    return (u16)(u >> 16);
}
// HW packed f32x2 -> bf16x2 (RNE), single VALU op (gfx940+)
__device__ __forceinline__ unsigned pkbf16(float a, float b) {
    unsigned d;
    asm("v_cvt_pk_bf16_f32 %0, %1, %2" : "=v"(d) : "v"(a), "v"(b));
    return d;
}
__device__ __forceinline__ float fexp2(float x) {
#if __has_builtin(__builtin_amdgcn_exp2f)
    return __builtin_amdgcn_exp2f(x);
#else
    return exp2f(x);
#endif
}
// async global->LDS, 16B per lane; LDS dest = wave-uniform base + lane*16
__device__ __forceinline__ void gl_lds16(const u16* g, u16* l) {
    __builtin_amdgcn_global_load_lds(
        (const __attribute__((address_space(1))) unsigned int*)g,
        (__attribute__((address_space(3))) unsigned int*)l,
        16, 0, 0);
}

// ---------------- fused prep: cast x + transpose/cast both weights --------
// grid: [0,8192) cast x ; [8192,11264) Wqkv^T ; [11264,12288) Wproj^T
__global__ __launch_bounds__(256) void prep(const float* __restrict__ x,
                                            const float* __restrict__ Wqkv,
                                            const float* __restrict__ Wproj,
                                            u16* __restrict__ xb,
                                            u16* __restrict__ WqkvT,
                                            u16* __restrict__ WprojT) {
    __shared__ float tile[32][33];
    int bid = blockIdx.x, tid = threadIdx.x;
    if (bid < 8192) {
        int i = bid * 1024 + tid * 4;
        float4 v = *(const float4*)(x + i);
        ushort4 o;
        o.x = f2b(v.x); o.y = f2b(v.y); o.z = f2b(v.z); o.w = f2b(v.w);
        *(ushort4*)(xb + i) = o;
        return;
    }
    const float* in; u16* outp; int N, bx, by;
    if (bid < 8192 + 3072) {
        int b2 = bid - 8192; bx = b2 % 96; by = b2 / 96;
        in = Wqkv; outp = WqkvT; N = 3 * C_EMBD;
    } else {
        int b2 = bid - 11264; bx = b2 % 32; by = b2 / 32;
        in = Wproj; outp = WprojT; N = C_EMBD;
    }
    int tx = tid & 31, ty = tid >> 5;
    int n0 = bx * 32, k0 = by * 32;
    for (int i = ty; i < 32; i += 8)
        tile[i][tx] = in[(size_t)(k0 + i) * N + n0 + tx];
    __syncthreads();
    for (int i = ty; i < 32; i += 8)
        outp[(size_t)(n0 + i) * C_EMBD + k0 + tx] = f2b(tile[tx][i]);
}

// ---------------- MFMA GEMM: qkv ----------------
// 128x128 tile, BK=32, 4 waves, double-buffered global_load_lds staging with
// strength-reduced pointers (ptr += 32/iter instead of full 64-bit recompute).
// A-frag: m=lane&15, k=quad*8+j ; C/D: row=quad*4+reg, col=lane&15.
// Epilogue: p=0 Q (pre-scaled 0.125*log2e) / p=1 K -> [B][H][T][hd] direct;
// p=2 V -> transposed [B][H][hd][T] via LDS round-trip (coalesced uint4),
// fusing away the former transpose_v kernel.
__global__ __launch_bounds__(256) void gemm_qkv(const u16* __restrict__ A,   // [8192][1024]
                                                const u16* __restrict__ BT,  // [3072][1024]
                                                const float* __restrict__ bias, // [3072]
                                                u16* __restrict__ qQ,
                                                u16* __restrict__ qK,
                                                u16* __restrict__ qVt) {
    const int NK = C_EMBD / 32;
    __shared__ __align__(16) u16 sS[2][2][128 * 32];   // [buf][A/B][rows*32]
    int m0 = blockIdx.y * 128;
    int n0 = blockIdx.x * 128;
    int tid = threadIdx.x;
    int w = tid >> 6, lane = tid & 63;
    int m_off = (w & 1) * 64, n_off = (w >> 1) * 64;
    int quad = lane >> 4, rl = lane & 15;
    int srow = lane >> 2, sko = (lane & 3) * 8;

    f32x4 acc[4][4];
    #pragma unroll
    for (int i = 0; i < 4; ++i)
        #pragma unroll
        for (int j = 0; j < 4; ++j)
            acc[i][j] = f32x4{0.f, 0.f, 0.f, 0.f};

    // wave w stages A rows [w*32,w*32+32) and B rows [w*32,w*32+32)
    const u16* gA0 = A + (size_t)(m0 + w * 32 + srow) * C_EMBD + sko;
    const u16* gA1 = gA0 + 16 * C_EMBD;
    const u16* gB0 = BT + (size_t)(n0 + w * 32 + srow) * C_EMBD + sko;
    const u16* gB1 = gB0 + 16 * C_EMBD;
    u16* lA[2] = { &sS[0][0][w * 32 * 32], &sS[1][0][w * 32 * 32] };
    u16* lB[2] = { &sS[0][1][w * 32 * 32], &sS[1][1][w * 32 * 32] };

    gl_lds16(gA0, lA[0]); gl_lds16(gA1, lA[0] + 512);
    gl_lds16(gB0, lB[0]); gl_lds16(gB1, lB[0] + 512);

    for (int kt = 0; kt < NK; ++kt) {
        __syncthreads();                       // drains prev prefetch; syncs buffers
        if (kt + 1 < NK) {
            gA0 += 32; gA1 += 32; gB0 += 32; gB1 += 32;
            int nb = (kt + 1) & 1;
            gl_lds16(gA0, lA[nb]); gl_lds16(gA1, lA[nb] + 512);
            gl_lds16(gB0, lB[nb]); gl_lds16(gB1, lB[nb] + 512);
        }
        const u16* pA = &sS[kt & 1][0][0];
        const u16* pB = &sS[kt & 1][1][0];
        bf16x8 af[4], bfr[4];
        #pragma unroll
        for (int i = 0; i < 4; ++i)
            af[i] = *(const bf16x8*)&pA[(m_off + i * 16 + rl) * 32 + quad * 8];
        #pragma unroll
        for (int j = 0; j < 4; ++j)
            bfr[j] = *(const bf16x8*)&pB[(n_off + j * 16 + rl) * 32 + quad * 8];
        #pragma unroll
        for (int i = 0; i < 4; ++i)
            #pragma unroll
            for (int j = 0; j < 4; ++j)
                acc[i][j] = __builtin_amdgcn_mfma_f32_16x16x32_bf16(af[i], bfr[j], acc[i][j], 0, 0, 0);
    }

    const float QSC = 0.18033688011112042f;   // 0.125 * log2(e)
    int p = n0 >> 10;                          // uniform per block (128 | 1024)
    if (p < 2) {
        u16* dst = p == 0 ? qQ : qK;
        float sc = p == 0 ? QSC : 1.0f;
        #pragma unroll
        for (int j = 0; j < 4; ++j) {
            int n = n0 + n_off + j * 16 + rl;
            float bv = bias[n];
            int cch = n & 1023;
            int h = cch >> 6, d = cch & 63;
            #pragma unroll
            for (int i = 0; i < 4; ++i) {
                int mbase = m0 + m_off + i * 16 + quad * 4;
                int bb = mbase >> 11, t0 = mbase & 2047;
                size_t thbase = ((size_t)bb * N_HEADC + h) * T_SEQ;
                #pragma unroll
                for (int r = 0; r < 4; ++r)
                    dst[(thbase + t0 + r) * HD + d] = f2b((acc[i][j][r] + bv) * sc);
            }
        }
    } else {
        // V: transpose 128n x 128m tile through LDS, store [bh][d][T] coalesced.
        u16 (*tr)[136] = (u16 (*)[136])&sS[0][0][0];   // 64 x 136 u16 = 17 KB
        int bb = m0 >> 11, t0g = m0 & 2047;
        #pragma unroll
        for (int half = 0; half < 2; ++half) {
            __syncthreads();   // staging reads (MFMA frags) / prev half stores done
            if (n_off == half * 64) {
                #pragma unroll
                for (int j = 0; j < 4; ++j) {
                    int rowr = j * 16 + rl;                     // d-row within half
                    float bv = bias[n0 + half * 64 + rowr];
                    #pragma unroll
                    for (int i = 0; i < 4; ++i) {
                        int mm = m_off + i * 16 + quad * 4;     // t within tile
                        *(unsigned*)&tr[rowr][mm]     = pkbf16(acc[i][j][0] + bv, acc[i][j][1] + bv);
                        *(unsigned*)&tr[rowr][mm + 2] = pkbf16(acc[i][j][2] + bv, acc[i][j][3] + bv);
                    }
                }
            }
            __syncthreads();
            #pragma unroll
            for (int s = 0; s < 4; ++s) {
                int task = s * 256 + tid;          // 1024 uint4 tasks
                int nn = task >> 4, seg = task & 15;
                int n = (n0 & 1023) + half * 64 + nn;
                int h = n >> 6, d = n & 63;
                size_t di = (((size_t)bb * N_HEADC + h) * HD + d) * T_SEQ + t0g + seg * 8;
                *(uint4*)&qVt[di] = *(const uint4*)&tr[nn][seg * 8];
            }
        }
    }
}

// proj: A = y_attn bf16 [8192][1024], BT = WprojT, out fp32 + bias
__global__ __launch_bounds__(256) void gemm_proj(const u16* __restrict__ A,
                                                 const u16* __restrict__ BT,
                                                 const float* __restrict__ bias,
                                                 float* __restrict__ out) {
    const int NK = C_EMBD / 32;
    __shared__ __align__(16) u16 sS[2][2][128 * 32];
    int m0 = blockIdx.y * 128;
    int n0 = blockIdx.x * 128;
    int tid = threadIdx.x;
    int w = tid >> 6, lane = tid & 63;
    int m_off = (w & 1) * 64, n_off = (w >> 1) * 64;
    int quad = lane >> 4, rl = lane & 15;
    int srow = lane >> 2, sko = (lane & 3) * 8;

    f32x4 acc[4][4];
    #pragma unroll
    for (int i = 0; i < 4; ++i)
        #pragma unroll
        for (int j = 0; j < 4; ++j)
            acc[i][j] = f32x4{0.f, 0.f, 0.f, 0.f};

    const u16* gA0 = A + (size_t)(m0 + w * 32 + srow) * C_EMBD + sko;
    const u16* gA1 = gA0 + 16 * C_EMBD;
    const u16* gB0 = BT + (size_t)(n0 + w * 32 + srow) * C_EMBD + sko;
    const u16* gB1 = gB0 + 16 * C_EMBD;
    u16* lA[2] = { &sS[0][0][w * 32 * 32], &sS[1][0][w * 32 * 32] };
    u16* lB[2] = { &sS[0][1][w * 32 * 32], &sS[1][1][w * 32 * 32] };

    gl_lds16(gA0, lA[0]); gl_lds16(gA1, lA[0] + 512);
    gl_lds16(gB0, lB[0]); gl_lds16(gB1, lB[0] + 512);

    for (int kt = 0; kt < NK; ++kt) {
        __syncthreads();
        if (kt + 1 < NK) {
            gA0 += 32; gA1 += 32; gB0 += 32; gB1 += 32;
            int nb = (kt + 1) & 1;
            gl_lds16(gA0, lA[nb]); gl_lds16(gA1, lA[nb] + 512);
            gl_lds16(gB0, lB[nb]); gl_lds16(gB1, lB[nb] + 512);
        }
        const u16* pA = &sS[kt & 1][0][0];
        const u16* pB = &sS[kt & 1][1][0];
        bf16x8 af[4], bfr[4];
        #pragma unroll
        for (int i = 0; i < 4; ++i)
            af[i] = *(const bf16x8*)&pA[(m_off + i * 16 + rl) * 32 + quad * 8];
        #pragma unroll
        for (int j = 0; j < 4; ++j)
            bfr[j] = *(const bf16x8*)&pB[(n_off + j * 16 + rl) * 32 + quad * 8];
        #pragma unroll
        for (int i = 0; i < 4; ++i)
            #pragma unroll
            for (int j = 0; j < 4; ++j)
                acc[i][j] = __builtin_amdgcn_mfma_f32_16x16x32_bf16(af[i], bfr[j], acc[i][j], 0, 0, 0);
    }

    #pragma unroll
    for (int i = 0; i < 4; ++i) {
        int mbase = m0 + m_off + i * 16 + quad * 4;
        #pragma unroll
        for (int j = 0; j < 4; ++j) {
            int n = n0 + n_off + j * 16 + rl;
            float bv = bias[n];
            #pragma unroll
            for (int r = 0; r < 4; ++r)
                out[(size_t)(mbase + r) * C_EMBD + n] = acc[i][j][r] + bv;
        }
    }
}

// ---------------- MFMA flash attention (causal, static-M softmax) ----------------
// grid (8, H, B), block 256 = 4 waves. Block bx does q-tiles (15-bx) then bx
// -> every block runs exactly 34 k-iterations (uniform length beats LPT).
// S^T = K.Q^T with C = -M folded into the accumulator -> p = exp2(s) direct.
// P packed via v_cvt_pk_bf16_f32; sP stride 72 u16 (16B-aligned b128 reads).
// K/Vt double-buffered via global_load_lds with strength-reduced pointers.
__global__ __launch_bounds__(256) void attn_mfma(const u16* __restrict__ Qg,
                                                 const u16* __restrict__ Kg,
                                                 const u16* __restrict__ Vtg,
                                                 u16* __restrict__ yb) {
    int bx = blockIdx.x, h = blockIdx.y, b = blockIdx.z;
    const size_t hs = (size_t)T_SEQ * HD;
    const u16* Qp  = Qg  + ((size_t)b * N_HEADC + h) * hs;  // [T][64] (pre-scaled)
    const u16* Kp  = Kg  + ((size_t)b * N_HEADC + h) * hs;  // [T][64]
    const u16* Vtp = Vtg + ((size_t)b * N_HEADC + h) * hs;  // [64][T]

    __shared__ __align__(16) u16 sK[2][2][64][32];   // [buf][d-half][kpos][d32]
    __shared__ __align__(16) u16 sVt[2][2][64][32];  // [buf][k-half][d][k32]
    __shared__ __align__(16) u16 sP[4][32][72];      // per-wave [q32][kpos64+pad8]

    int tid = threadIdx.x;
    int lane = tid & 63, w = tid >> 6;
    int quad = lane >> 4, rl = lane & 15;
    u16* sPw = &sP[w][0][0];
    int srow = lane >> 2;            // staging: row within 16-row chunk
    int sch = (lane & 3) * 8;        // staging: 8-elem piece
    const f32x4 mneg = {-16.f, -16.f, -16.f, -16.f};   // -SOFT_M folded into C

    // staging pointers/dests: wave 0/1 = K halves, wave 2/3 = Vt halves
    const u16* gp0[4];
    u16* ld0[4]; u16* ld1[4];
    int gstep;
    if (w < 2) {
        gstep = 64 * HD;
        #pragma unroll
        for (int c = 0; c < 4; ++c) {
            gp0[c] = Kp + (size_t)(c * 16 + srow) * HD + w * 32 + sch;
            ld0[c] = &sK[0][w][c * 16][0];
            ld1[c] = &sK[1][w][c * 16][0];
        }
    } else {
        gstep = 64;
        #pragma unroll
        for (int c = 0; c < 4; ++c) {
            gp0[c] = Vtp + (size_t)(c * 16 + srow) * T_SEQ + (w - 2) * 32 + sch;
            ld0[c] = &sVt[0][w - 2][c * 16][0];
            ld1[c] = &sVt[1][w - 2][c * 16][0];
        }
    }

    #pragma unroll
    for (int phase = 0; phase < 2; ++phase) {
        int qt = phase == 0 ? (15 - bx) : bx;
        int q0w = qt * 128 + w * 32;
        int nkt = 2 * qt + 2;

        // Q fragments (B-operand of S^T)
        bf16x8 qf[2][2];
        #pragma unroll
        for (int nt = 0; nt < 2; ++nt)
            #pragma unroll
            for (int ks = 0; ks < 2; ++ks)
                qf[nt][ks] = *(const bf16x8*)&Qp[(size_t)(q0w + nt * 16 + rl) * HD + ks * 32 + quad * 8];

        f32x4 O[2][4];
        #pragma unroll
        for (int mi = 0; mi < 2; ++mi)
            #pragma unroll
            for (int nd = 0; nd < 4; ++nd)
                O[mi][nd] = f32x4{0.f, 0.f, 0.f, 0.f};
        float l_[2] = {0.f, 0.f};

        const u16* gp[4];
        #pragma unroll
        for (int c = 0; c < 4; ++c) gp[c] = gp0[c];

        __syncthreads();   // prev phase's readers done before restaging buf0
        #pragma unroll
        for (int c = 0; c < 4; ++c) gl_lds16(gp[c], ld0[c]);

        for (int kt = 0; kt < nkt; ++kt) {
            __syncthreads();          // drains stage(kt); syncs buffers
            int buf = kt & 1;
            int k0 = kt * 64;
            if (kt + 1 < nkt) {       // prefetch kt+1 into other buffer
                u16* const* ldn = ((kt + 1) & 1) ? ld1 : ld0;
                #pragma unroll
                for (int c = 0; c < 4; ++c) {
                    gp[c] += gstep;
                    gl_lds16(gp[c], ldn[c]);
                }
            }
            if (k0 > q0w + 31) continue;   // this wave's rows fully masked

            // S^T = K . Q^T - M : rows kpos=k0+mt*16+quad*4+r, col q=q0w+nt*16+rl
            f32x4 st[4][2];
            #pragma unroll
            for (int mt = 0; mt < 4; ++mt) {
                bf16x8 ak0 = *(const bf16x8*)&sK[buf][0][mt * 16 + rl][quad * 8];
                bf16x8 ak1 = *(const bf16x8*)&sK[buf][1][mt * 16 + rl][quad * 8];
                #pragma unroll
                for (int nt = 0; nt < 2; ++nt) {
                    f32x4 t = __builtin_amdgcn_mfma_f32_16x16x32_bf16(ak0, qf[nt][0], mneg, 0, 0, 0);
                    st[mt][nt] = __builtin_amdgcn_mfma_f32_16x16x32_bf16(ak1, qf[nt][1], t, 0, 0, 0);
                }
            }

            if (k0 + 63 > q0w) {   // diagonal tile: causal mask
                #pragma unroll
                for (int mt = 0; mt < 4; ++mt)
                    #pragma unroll
                    for (int nt = 0; nt < 2; ++nt)
                        #pragma unroll
                        for (int r = 0; r < 4; ++r) {
                            int kpos = k0 + mt * 16 + quad * 4 + r;
                            int q = q0w + nt * 16 + rl;
                            if (kpos > q) st[mt][nt][r] = -INFINITY;
                        }
            }

            // static-M softmax: p = exp2(s); lane-local l accumulation
            #pragma unroll
            for (int nt = 0; nt < 2; ++nt) {
                float lsum = 0.f;
                #pragma unroll
                for (int mt = 0; mt < 4; ++mt) {
                    float p0 = fexp2(st[mt][nt][0]);
                    float p1 = fexp2(st[mt][nt][1]);
                    float p2 = fexp2(st[mt][nt][2]);
                    float p3 = fexp2(st[mt][nt][3]);
                    lsum += (p0 + p1) + (p2 + p3);
                    *(uint2*)&sPw[(nt * 16 + rl) * 72 + mt * 16 + quad * 4] =
                        make_uint2(pkbf16(p0, p1), pkbf16(p2, p3));
                }
                l_[nt] += lsum;
            }

            // O += P . V  (A=P from own LDS region, B=V^T)
            #pragma unroll
            for (int ks = 0; ks < 2; ++ks) {
                bf16x8 ap0 = *(const bf16x8*)&sPw[(0 * 16 + rl) * 72 + ks * 32 + quad * 8];
                bf16x8 ap1 = *(const bf16x8*)&sPw[(1 * 16 + rl) * 72 + ks * 32 + quad * 8];
                #pragma unroll
                for (int nd = 0; nd < 4; ++nd) {
                    bf16x8 bv = *(const bf16x8*)&sVt[buf][ks][nd * 16 + rl][quad * 8];
                    O[0][nd] = __builtin_amdgcn_mfma_f32_16x16x32_bf16(ap0, bv, O[0][nd], 0, 0, 0);
                    O[1][nd] = __builtin_amdgcn_mfma_f32_16x16x32_bf16(ap1, bv, O[1][nd], 0, 0, 0);
                }
            }
        }

        // epilogue: reduce l across quads, write y[b*T+q][h*64+d] = O/l
        #pragma unroll
        for (int nt = 0; nt < 2; ++nt) {
            l_[nt] += __shfl_xor(l_[nt], 16);
            l_[nt] += __shfl_xor(l_[nt], 32);
        }
        float linv[2] = {1.f / l_[0], 1.f / l_[1]};
        int idxq = quad * 4;
        #pragma unroll
        for (int mi = 0; mi < 2; ++mi)
            #pragma unroll
            for (int r = 0; r < 4; ++r) {
                float li = __shfl(linv[mi], idxq + r);
                int qg = q0w + mi * 16 + quad * 4 + r;
                size_t base = ((size_t)b * T_SEQ + qg) * C_EMBD + h * HD;
                #pragma unroll
                for (int nd = 0; nd < 4; ++nd)
                    yb[base + nd * 16 + rl] = f2b(O[mi][nd][r] * li);
            }
    }
}

// ---------------- launch ----------------
// workspace layout (bytes):
//   xb     @ 0      : 16 MB  bf16 [8192][1024]
//   WqkvT  @ 16 MB  :  6 MB  bf16 [3072][1024]
//   WprojT @ 22 MB  :  2 MB  bf16 [1024][1024]
//   qQ     @ 24 MB  : 16 MB  bf16 [B][H][T][64] (pre-scaled by 0.125*log2e)
//   qK     @ 40 MB  : 16 MB  bf16 [B][H][T][64]
//   qVt    @ 56 MB  : 16 MB  bf16 [B][H][64][T] (written directly by gemm_qkv)
//   yb     @ 72 MB  : 16 MB  bf16 [8192][1024]
extern "C" void kernel_launch(void* const* d_in, const int* in_sizes, int n_in,
                              void* d_out, int out_size, void* d_ws, size_t ws_size,
                              hipStream_t stream) {
    const float* x     = (const float*)d_in[0];
    const float* Wqkv  = (const float*)d_in[1];
    const float* bqkv  = (const float*)d_in[2];
    const float* Wproj = (const float*)d_in[3];
    const float* bproj = (const float*)d_in[4];
    float* out = (float*)d_out;

    char* ws = (char*)d_ws;
    u16* xb     = (u16*)(ws);
    u16* WqkvT  = (u16*)(ws + (size_t)16 * 1024 * 1024);
    u16* WprojT = (u16*)(ws + (size_t)22 * 1024 * 1024);
    u16* qQ     = (u16*)(ws + (size_t)24 * 1024 * 1024);
    u16* qK     = (u16*)(ws + (size_t)40 * 1024 * 1024);
    u16* qVt    = (u16*)(ws + (size_t)56 * 1024 * 1024);
    u16* yb     = (u16*)(ws + (size_t)72 * 1024 * 1024);

    prep<<<dim3(12288), dim3(256), 0, stream>>>(x, Wqkv, Wproj, xb, WqkvT, WprojT);
    gemm_qkv<<<dim3(3 * C_EMBD / 128, M_TOT / 128), dim3(256), 0, stream>>>(
        xb, WqkvT, bqkv, qQ, qK, qVt);
    attn_mfma<<<dim3(8, N_HEADC, B_SZ), dim3(256), 0, stream>>>(
        qQ, qK, qVt, yb);
    gemm_proj<<<dim3(C_EMBD / 128, M_TOT / 128), dim3(256), 0, stream>>>(
        yb, WprojT, bproj, out);
}